// Round 1
// baseline (714.378 us; speedup 1.0000x reference)
//
#include <hip/hip_runtime.h>

// Sizes
#define BB 16
#define IC 8
#define OC 8
#define NV 3
#define M1 16
#define M2 16
#define TD 256
#define HH 256
#define WW 256
// derived
#define NIMG_IN  (BB*IC*NV)   // 384
#define NIMG_OUT (BB*OC*NV)   // 384
#define NROWS    (IC*OC*NV*M1*M2)  // 49152
#define TWO_PI 6.28318530717958647692f

// ---------------------------------------------------------------------------
// K1: partial forward DFT. One block per input image (b,i,v).
// Computes Xf[img][row*16+ky], row 0..15 -> kx=row (top), row 16..31 -> kx=224+row (bot),
// using conjugate symmetry: y[kx] for kx=0..16 only.
// ---------------------------------------------------------------------------
__global__ __launch_bounds__(256) void k1_fwd_dft(const float* __restrict__ x,
                                                  float2* __restrict__ Xf) {
  __shared__ float2 E[17 * 257];   // twiddle rows kx=0..16, padded pitch
  __shared__ float2 yb[17 * 257];  // y[kx][w], padded pitch

  const int tid = threadIdx.x;
  const int img = blockIdx.x;  // b*24 + i*3 + v
  const float* xp = x + (size_t)img * (HH * WW);

  // Build twiddle table E[k][n] = (cos, sin)(2*pi*((k*n)&255)/256)
  for (int n = tid; n < 17 * 256; n += 256) {
    int k = n >> 8, h = n & 255;
    int m = (k * h) & 255;
    float ang = (float)m * (TWO_PI / 256.0f);
    float s, c;
    sincosf(ang, &s, &c);
    E[k * 257 + h] = make_float2(c, s);
  }
  __syncthreads();

  // Stage A: y[kx][w] = sum_h e^{-2pi i kx h/256} x[h][w], kx = 0..16
  float yr[17], yi[17];
#pragma unroll
  for (int k = 0; k < 17; k++) { yr[k] = 0.0f; yi[k] = 0.0f; }
  const int w = tid;
  for (int h = 0; h < 256; h++) {
    float xv = xp[h * 256 + w];
#pragma unroll
    for (int k = 0; k < 17; k++) {
      float2 e = E[k * 257 + h];
      yr[k] = fmaf(e.x, xv, yr[k]);
      yi[k] = fmaf(-e.y, xv, yi[k]);
    }
  }
#pragma unroll
  for (int k = 0; k < 17; k++) yb[k * 257 + w] = make_float2(yr[k], yi[k]);
  __syncthreads();

  // Stage B: Xf[row][ky] = sum_w y_eff[kx][w] * e^{-2pi i ky w/256}
  // row<16: y_eff = y[row]; row>=16 (kx=224+row): y_eff = conj(y[32-row])
  float2* XfImg = Xf + (size_t)img * 512;
  for (int n = tid; n < 512; n += 256) {
    int row = n >> 4, ky = n & 15;
    int kxl = (row < 16) ? row : (32 - row);
    float sgn = (row < 16) ? 1.0f : -1.0f;
    float Xr = 0.0f, Xi = 0.0f;
    for (int ww2 = 0; ww2 < 256; ww2++) {
      float2 y = yb[kxl * 257 + ww2];
      float2 e = E[ky * 257 + ww2];
      float yy = y.y * sgn;
      Xr += y.x * e.x + yy * e.y;
      Xi += yy * e.x - y.x * e.y;
    }
    XfImg[n] = make_float2(Xr, Xi);
  }
}

// ---------------------------------------------------------------------------
// K2: temporal weight contraction tw[b][row] = sum_t t[b][t] * w[row][t]
// lane = rl*16 + b : 4 rows/wave, 16 b per row. Row load is one broadcast
// float4 shared by 16 lanes. t in padded LDS (bank-conflict-free).
// grid: 3072 blocks x 256 threads -> 3072*4 waves * 4 rows = 49152 rows.
// ---------------------------------------------------------------------------
__global__ __launch_bounds__(256) void k2_tw(const float* __restrict__ t,
                                             const float* __restrict__ w1r,
                                             const float* __restrict__ w1i,
                                             const float* __restrict__ w2r,
                                             const float* __restrict__ w2i,
                                             float2* __restrict__ tw1,
                                             float2* __restrict__ tw2) {
  __shared__ float tL[16 * 257];
  const int tid = threadIdx.x;
  for (int n = tid; n < 16 * 256; n += 256) {
    int b = n >> 8, tt = n & 255;
    tL[b * 257 + tt] = t[b * 256 + tt];
  }
  __syncthreads();

  const int lane = tid & 63;
  const int wv = tid >> 6;
  const int b = lane & 15;
  const int rl = lane >> 4;
  const int row = (blockIdx.x * 4 + wv) * 4 + rl;  // 0..49151

  const float4* p1r = (const float4*)(w1r + (size_t)row * 256);
  const float4* p1i = (const float4*)(w1i + (size_t)row * 256);
  const float4* p2r = (const float4*)(w2r + (size_t)row * 256);
  const float4* p2i = (const float4*)(w2i + (size_t)row * 256);
  const float* tb = tL + b * 257;

  float a1r = 0.0f, a1i = 0.0f, a2r = 0.0f, a2i = 0.0f;
  for (int ti = 0; ti < 64; ti++) {
    float4 v1r = p1r[ti];
    float4 v1i = p1i[ti];
    float4 v2r = p2r[ti];
    float4 v2i = p2i[ti];
    float t0 = tb[4 * ti + 0];
    float t1 = tb[4 * ti + 1];
    float t2 = tb[4 * ti + 2];
    float t3 = tb[4 * ti + 3];
    a1r += t0 * v1r.x + t1 * v1r.y + t2 * v1r.z + t3 * v1r.w;
    a1i += t0 * v1i.x + t1 * v1i.y + t2 * v1i.z + t3 * v1i.w;
    a2r += t0 * v2r.x + t1 * v2r.y + t2 * v2r.z + t3 * v2r.w;
    a2i += t0 * v2i.x + t1 * v2i.y + t2 * v2i.z + t3 * v2i.w;
  }
  tw1[(size_t)b * NROWS + row] = make_float2(a1r, a1i);
  tw2[(size_t)b * NROWS + row] = make_float2(a2r, a2i);
}

// ---------------------------------------------------------------------------
// K3: spectral mixing over input channels.
// ft_top[b,o,v,x,y] = sum_i Xf_top[b,i,v,x,y] * tw1[b,i,o,v,x,y]  (same for bot/tw2)
// ---------------------------------------------------------------------------
__global__ __launch_bounds__(256) void k3_mix(const float2* __restrict__ Xf,
                                              const float2* __restrict__ tw1,
                                              const float2* __restrict__ tw2,
                                              float2* __restrict__ ftT,
                                              float2* __restrict__ ftB) {
  const int n = blockIdx.x * 256 + threadIdx.x;  // 0..98303 : (b,o,v,xy)
  const int xy = n & 255;
  const int ov = n >> 8;
  const int v = ov % 3;
  const int o = (ov / 3) & 7;
  const int b = n / (OC * NV * 256);

  float tr = 0.0f, ti2 = 0.0f, br = 0.0f, bi = 0.0f;
#pragma unroll
  for (int i = 0; i < IC; i++) {
    const float2 xt = Xf[(size_t)(((b * IC + i) * NV + v) << 9) + xy];
    const float2 xb = Xf[(size_t)(((b * IC + i) * NV + v) << 9) + 256 + xy];
    const int r = ((i * OC + o) * NV + v) * 256 + xy;
    float2 u1 = tw1[(size_t)b * NROWS + r];
    float2 u2 = tw2[(size_t)b * NROWS + r];
    tr += xt.x * u1.x - xt.y * u1.y;
    ti2 += xt.x * u1.y + xt.y * u1.x;
    br += xb.x * u2.x - xb.y * u2.y;
    bi += xb.x * u2.y + xb.y * u2.x;
  }
  const int nout = ((b * OC + o) * NV + v) * 256 + xy;
  ftT[nout] = make_float2(tr, ti2);
  ftB[nout] = make_float2(br, bi);
}

// ---------------------------------------------------------------------------
// K4: partial inverse transform. One block per output image (b,o,v).
// out[h][w] = Re( sum_ky P[w][ky] * G[h][ky] ),
// G[h][ky] = sum_{row in 32 modes} ft[row][ky] e^{+2pi i kx h/256},
// P[w][ky] = (c_ky/65536) e^{+2pi i ky w/256}, c_0=1, c_ky=2.
// ---------------------------------------------------------------------------
__global__ __launch_bounds__(256) void k4_inv(const float2* __restrict__ ftT,
                                              const float2* __restrict__ ftB,
                                              float* __restrict__ out) {
  __shared__ float2 tbl[256];
  __shared__ float2 ftL[512];       // [row 0..31][ky 0..15]
  __shared__ float2 G[256 * 17];    // [h][ky], padded pitch 17
  __shared__ float2 P[256 * 17];    // [w][ky], padded pitch 17

  const int tid = threadIdx.x;
  const int img = blockIdx.x;  // (b*8+o)*3+v

  // twiddle table + ft load
  {
    float s, c;
    sincosf((float)tid * (TWO_PI / 256.0f), &s, &c);
    tbl[tid] = make_float2(c, s);
    ftL[tid] = ftT[(size_t)img * 256 + tid];
    ftL[256 + tid] = ftB[(size_t)img * 256 + tid];
  }
  __syncthreads();

  // Build P (thread = w) and G (thread = h)
  {
    const int w = tid;
#pragma unroll
    for (int ky = 0; ky < 16; ky++) {
      float2 e = tbl[(ky * w) & 255];
      float sc = (ky == 0 ? 1.0f : 2.0f) * (1.0f / 65536.0f);
      P[w * 17 + ky] = make_float2(e.x * sc, e.y * sc);
    }
  }
  {
    const int h = tid;
    float gr[16], gi[16];
#pragma unroll
    for (int ky = 0; ky < 16; ky++) { gr[ky] = 0.0f; gi[ky] = 0.0f; }
    for (int row = 0; row < 32; row++) {
      int kxv = (row < 16) ? row : (224 + row);  // 240 + (row-16)
      float2 e = tbl[(kxv * h) & 255];
#pragma unroll
      for (int ky = 0; ky < 16; ky++) {
        float2 f = ftL[row * 16 + ky];
        gr[ky] += f.x * e.x - f.y * e.y;
        gi[ky] += f.x * e.y + f.y * e.x;
      }
    }
#pragma unroll
    for (int ky = 0; ky < 16; ky++) G[h * 17 + ky] = make_float2(gr[ky], gi[ky]);
  }
  __syncthreads();

  // Stage 2: real contraction over ky
  const int wt = tid & 31;
  const int ht = tid >> 5;
  float* obase = out + (size_t)img * (HH * WW);
  for (int hh = ht; hh < 256; hh += 8) {
    float2 g[16];
#pragma unroll
    for (int ky = 0; ky < 16; ky++) g[ky] = G[hh * 17 + ky];
    float* orow = obase + hh * 256;
#pragma unroll
    for (int j = 0; j < 8; j++) {
      int w = wt + 32 * j;
      float acc = 0.0f;
#pragma unroll
      for (int ky = 0; ky < 16; ky++) {
        float2 p = P[w * 17 + ky];
        acc += g[ky].x * p.x - g[ky].y * p.y;
      }
      orow[w] = acc;
    }
  }
}

// ---------------------------------------------------------------------------
extern "C" void kernel_launch(void* const* d_in, const int* in_sizes, int n_in,
                              void* d_out, int out_size, void* d_ws, size_t ws_size,
                              hipStream_t stream) {
  const float* t = (const float*)d_in[0];
  const float* x = (const float*)d_in[1];
  const float* w1r = (const float*)d_in[2];
  const float* w1i = (const float*)d_in[3];
  const float* w2r = (const float*)d_in[4];
  const float* w2i = (const float*)d_in[5];
  float* out = (float*)d_out;

  float2* ws = (float2*)d_ws;
  float2* Xf = ws;                       // 384*512      = 196608 float2
  float2* tw1 = Xf + 196608;             // 16*49152     = 786432 float2
  float2* tw2 = tw1 + 786432;            // 786432 float2
  float2* ftT = tw2 + 786432;            // 98304 float2
  float2* ftB = ftT + 98304;             // 98304 float2  (total ~16.5 MB)

  k1_fwd_dft<<<NIMG_IN, 256, 0, stream>>>(x, Xf);
  k2_tw<<<NROWS / 16, 256, 0, stream>>>(t, w1r, w1i, w2r, w2i, tw1, tw2);
  k3_mix<<<(BB * OC * NV * 256) / 256, 256, 0, stream>>>(Xf, tw1, tw2, ftT, ftB);
  k4_inv<<<NIMG_OUT, 256, 0, stream>>>(ftT, ftB, out);
}

// Round 2
// 513.875 us; speedup vs baseline: 1.3902x; 1.3902x over previous
//
#include <hip/hip_runtime.h>

// Sizes
#define BB 16
#define IC 8
#define OC 8
#define NV 3
#define M1 16
#define M2 16
#define HH 256
#define WW 256
#define NIMG_IN  (BB*IC*NV)        // 384
#define NIMG_OUT (BB*OC*NV)        // 384
#define NROWS    (IC*OC*NV*M1*M2)  // 49152
#define TWO_PI 6.28318530717958647692f

// ---------------------------------------------------------------------------
// K1a: row DFT, kx-split for occupancy. grid = 768 (img, kxhalf).
// y[img][kx][w] = sum_h e^{-2pi i kx h/256} x[h][w], kx in 0..16.
// ---------------------------------------------------------------------------
__global__ __launch_bounds__(256) void k1a_rowdft(const float* __restrict__ x,
                                                  float2* __restrict__ y) {
  __shared__ float2 tbl[256];
  const int tid = threadIdx.x;
  const int img = blockIdx.x >> 1;
  const int half = blockIdx.x & 1;
  const int kbase = half ? 9 : 0;
  const int kcount = half ? 8 : 9;
  {
    float s, c;
    sincosf((float)tid * (TWO_PI / 256.0f), &s, &c);
    tbl[tid] = make_float2(c, s);
  }
  __syncthreads();

  const float* xp = x + (size_t)img * 65536 + tid;
  float yr[9], yi[9];
#pragma unroll
  for (int k = 0; k < 9; k++) { yr[k] = 0.0f; yi[k] = 0.0f; }

  int mb = 0;  // (kbase*h)&255
#pragma unroll 4
  for (int h = 0; h < 256; h++) {
    float xv = xp[h * 256];
    int m = mb;
#pragma unroll
    for (int k = 0; k < 9; k++) {
      float2 e = tbl[m];
      yr[k] = fmaf(e.x, xv, yr[k]);
      yi[k] = fmaf(-e.y, xv, yi[k]);
      m = (m + h) & 255;
    }
    mb = (mb + kbase) & 255;
  }
  float2* yo = y + (size_t)img * 4352 + (size_t)kbase * 256 + tid;
  for (int k = 0; k < kcount; k++) yo[k * 256] = make_float2(yr[k], yi[k]);
}

// ---------------------------------------------------------------------------
// K1b: column DFT over retained ky modes. grid = 384 (img).
// Xf[img][row*16+ky]; row<16 -> kx=row, row>=16 -> kx=224+row (conj symmetry).
// ---------------------------------------------------------------------------
__global__ __launch_bounds__(256) void k1b_coldft(const float2* __restrict__ y,
                                                  float2* __restrict__ Xf) {
  __shared__ float2 tbl[256];
  __shared__ float2 yb[17 * 257];
  const int tid = threadIdx.x;
  const int img = blockIdx.x;
  {
    float s, c;
    sincosf((float)tid * (TWO_PI / 256.0f), &s, &c);
    tbl[tid] = make_float2(c, s);
  }
  const float2* yg = y + (size_t)img * 4352;
  for (int n = tid; n < 4352; n += 256) {
    int kx = n >> 8, w = n & 255;
    yb[kx * 257 + w] = yg[n];
  }
  __syncthreads();

  float2* XfImg = Xf + (size_t)img * 512;
  for (int n = tid; n < 512; n += 256) {
    int row = n >> 4, ky = n & 15;
    int kxl = (row < 16) ? row : (32 - row);
    float sgn = (row < 16) ? 1.0f : -1.0f;
    float Xr = 0.0f, Xi = 0.0f;
    int m = 0;
    for (int w2 = 0; w2 < 256; w2++) {
      float2 yv = yb[kxl * 257 + w2];
      float2 e = tbl[m];  // (ky*w2)&255
      m = (m + ky) & 255;
      float yy = yv.y * sgn;
      Xr += yv.x * e.x + yy * e.y;
      Xi += yy * e.x - yv.x * e.y;
    }
    XfImg[n] = make_float2(Xr, Xi);
  }
}

// ---------------------------------------------------------------------------
// K2: temporal weight contraction tw[b][row] = sum_t t[b][t] * w[row][t]
// ---------------------------------------------------------------------------
__global__ __launch_bounds__(256) void k2_tw(const float* __restrict__ t,
                                             const float* __restrict__ w1r,
                                             const float* __restrict__ w1i,
                                             const float* __restrict__ w2r,
                                             const float* __restrict__ w2i,
                                             float2* __restrict__ tw1,
                                             float2* __restrict__ tw2) {
  __shared__ float tL[16 * 257];
  const int tid = threadIdx.x;
  for (int n = tid; n < 16 * 256; n += 256) {
    int b = n >> 8, tt = n & 255;
    tL[b * 257 + tt] = t[b * 256 + tt];
  }
  __syncthreads();

  const int lane = tid & 63;
  const int wv = tid >> 6;
  const int b = lane & 15;
  const int rl = lane >> 4;
  const int row = (blockIdx.x * 4 + wv) * 4 + rl;

  const float4* p1r = (const float4*)(w1r + (size_t)row * 256);
  const float4* p1i = (const float4*)(w1i + (size_t)row * 256);
  const float4* p2r = (const float4*)(w2r + (size_t)row * 256);
  const float4* p2i = (const float4*)(w2i + (size_t)row * 256);
  const float* tb = tL + b * 257;

  float a1r = 0.0f, a1i = 0.0f, a2r = 0.0f, a2i = 0.0f;
  for (int ti = 0; ti < 64; ti++) {
    float4 v1r = p1r[ti];
    float4 v1i = p1i[ti];
    float4 v2r = p2r[ti];
    float4 v2i = p2i[ti];
    float t0 = tb[4 * ti + 0];
    float t1 = tb[4 * ti + 1];
    float t2 = tb[4 * ti + 2];
    float t3 = tb[4 * ti + 3];
    a1r += t0 * v1r.x + t1 * v1r.y + t2 * v1r.z + t3 * v1r.w;
    a1i += t0 * v1i.x + t1 * v1i.y + t2 * v1i.z + t3 * v1i.w;
    a2r += t0 * v2r.x + t1 * v2r.y + t2 * v2r.z + t3 * v2r.w;
    a2i += t0 * v2i.x + t1 * v2i.y + t2 * v2i.z + t3 * v2i.w;
  }
  tw1[(size_t)b * NROWS + row] = make_float2(a1r, a1i);
  tw2[(size_t)b * NROWS + row] = make_float2(a2r, a2i);
}

// ---------------------------------------------------------------------------
// K3: spectral mixing over input channels.
// ---------------------------------------------------------------------------
__global__ __launch_bounds__(256) void k3_mix(const float2* __restrict__ Xf,
                                              const float2* __restrict__ tw1,
                                              const float2* __restrict__ tw2,
                                              float2* __restrict__ ftT,
                                              float2* __restrict__ ftB) {
  const int n = blockIdx.x * 256 + threadIdx.x;
  const int xy = n & 255;
  const int ov = n >> 8;
  const int v = ov % 3;
  const int o = (ov / 3) & 7;
  const int b = n / (OC * NV * 256);

  float tr = 0.0f, ti2 = 0.0f, br = 0.0f, bi = 0.0f;
#pragma unroll
  for (int i = 0; i < IC; i++) {
    const float2 xt = Xf[(size_t)(((b * IC + i) * NV + v) << 9) + xy];
    const float2 xb = Xf[(size_t)(((b * IC + i) * NV + v) << 9) + 256 + xy];
    const int r = ((i * OC + o) * NV + v) * 256 + xy;
    float2 u1 = tw1[(size_t)b * NROWS + r];
    float2 u2 = tw2[(size_t)b * NROWS + r];
    tr += xt.x * u1.x - xt.y * u1.y;
    ti2 += xt.x * u1.y + xt.y * u1.x;
    br += xb.x * u2.x - xb.y * u2.y;
    bi += xb.x * u2.y + xb.y * u2.x;
  }
  const int nout = ((b * OC + o) * NV + v) * 256 + xy;
  ftT[nout] = make_float2(tr, ti2);
  ftB[nout] = make_float2(br, bi);
}

// ---------------------------------------------------------------------------
// K4a: h-direction inverse: G[img][ky][h] = sum_row ft[row][ky] e^{+2pi i kx_row h/256}
// grid = 384. Light LDS (6 KB), ~64 VGPR.
// ---------------------------------------------------------------------------
__global__ __launch_bounds__(256) void k4a_hdft(const float2* __restrict__ ftT,
                                                const float2* __restrict__ ftB,
                                                float2* __restrict__ G) {
  __shared__ float2 tbl[256];
  __shared__ float2 ftL[512];
  const int tid = threadIdx.x;
  const int img = blockIdx.x;
  {
    float s, c;
    sincosf((float)tid * (TWO_PI / 256.0f), &s, &c);
    tbl[tid] = make_float2(c, s);
    ftL[tid] = ftT[(size_t)img * 256 + tid];
    ftL[256 + tid] = ftB[(size_t)img * 256 + tid];
  }
  __syncthreads();

  const int h = tid;
  float gr[16], gi[16];
#pragma unroll
  for (int ky = 0; ky < 16; ky++) { gr[ky] = 0.0f; gi[ky] = 0.0f; }
  for (int row = 0; row < 32; row++) {
    int kxv = (row < 16) ? row : (224 + row);
    float2 e = tbl[(kxv * h) & 255];
#pragma unroll
    for (int ky = 0; ky < 16; ky++) {
      float2 f = ftL[row * 16 + ky];
      gr[ky] += f.x * e.x - f.y * e.y;
      gi[ky] += f.x * e.y + f.y * e.x;
    }
  }
  float2* Gi = G + (size_t)img * 4096;
#pragma unroll
  for (int ky = 0; ky < 16; ky++) Gi[ky * 256 + h] = make_float2(gr[ky], gi[ky]);
}

// ---------------------------------------------------------------------------
// K4b: w-direction inverse + write. grid = 384*8 (img, h-tile of 32).
// out[h][w] = sum_ky Re(P[ky][w] * G[ky][h]); P folds c_ky/(H*W).
// Thread: w0=lane (4 cols), hq=wave (8 rows) -> acc[8][4]. G reads are
// wave-uniform broadcasts; P reads consecutive (conflict-free).
// ---------------------------------------------------------------------------
__global__ __launch_bounds__(256) void k4b_wdft(const float2* __restrict__ G,
                                                float* __restrict__ out) {
  __shared__ float2 tbl[256];
  __shared__ float2 PL[16 * 256];
  __shared__ float2 gt[512];  // [ky][hh], pitch 32
  const int tid = threadIdx.x;
  const int img = blockIdx.x >> 3;
  const int h0 = (blockIdx.x & 7) * 32;
  {
    float s, c;
    sincosf((float)tid * (TWO_PI / 256.0f), &s, &c);
    tbl[tid] = make_float2(c, s);
  }
  __syncthreads();
  for (int n = tid; n < 4096; n += 256) {
    int ky = n >> 8, w = n & 255;
    float2 e = tbl[(ky * w) & 255];
    float sc = (ky == 0) ? (1.0f / 65536.0f) : (2.0f / 65536.0f);
    PL[n] = make_float2(e.x * sc, e.y * sc);
  }
  const float2* Gi = G + (size_t)img * 4096;
  for (int n = tid; n < 512; n += 256) {
    int ky = n >> 5, hh = n & 31;
    gt[n] = Gi[ky * 256 + h0 + hh];
  }
  __syncthreads();

  const int w0 = tid & 63;
  const int hq = tid >> 6;
  float acc[8][4];
#pragma unroll
  for (int a = 0; a < 8; a++)
#pragma unroll
    for (int j = 0; j < 4; j++) acc[a][j] = 0.0f;

#pragma unroll 4
  for (int ky = 0; ky < 16; ky++) {
    float2 p0 = PL[ky * 256 + w0];
    float2 p1 = PL[ky * 256 + w0 + 64];
    float2 p2 = PL[ky * 256 + w0 + 128];
    float2 p3 = PL[ky * 256 + w0 + 192];
#pragma unroll
    for (int a = 0; a < 8; a++) {
      float2 g = gt[ky * 32 + hq * 8 + a];
      acc[a][0] += g.x * p0.x - g.y * p0.y;
      acc[a][1] += g.x * p1.x - g.y * p1.y;
      acc[a][2] += g.x * p2.x - g.y * p2.y;
      acc[a][3] += g.x * p3.x - g.y * p3.y;
    }
  }
  float* obase = out + (size_t)img * 65536 + (size_t)(h0 + hq * 8) * 256;
#pragma unroll
  for (int a = 0; a < 8; a++) {
#pragma unroll
    for (int j = 0; j < 4; j++) obase[a * 256 + w0 + 64 * j] = acc[a][j];
  }
}

// ---------------------------------------------------------------------------
extern "C" void kernel_launch(void* const* d_in, const int* in_sizes, int n_in,
                              void* d_out, int out_size, void* d_ws, size_t ws_size,
                              hipStream_t stream) {
  const float* t = (const float*)d_in[0];
  const float* x = (const float*)d_in[1];
  const float* w1r = (const float*)d_in[2];
  const float* w1i = (const float*)d_in[3];
  const float* w2r = (const float*)d_in[4];
  const float* w2i = (const float*)d_in[5];
  float* out = (float*)d_out;

  // Workspace aliasing (stream-ordered lifetimes keep this safe):
  //   R1: y (K1a->K1b) -> tw1,tw2 (K2->K3) -> G (K4a->K4b)   [1,671,168 f2]
  //   Xf: K1b->K3   [196,608 f2]
  //   ftT/ftB: K3->K4a [2*98,304 f2]
  // Total: 2,064,384 float2 = 16.5 MB.
  float2* R1 = (float2*)d_ws;
  float2* y = R1;
  float2* tw1 = R1;
  float2* tw2 = R1 + 786432;
  float2* G = R1;
  float2* Xf = R1 + 1671168;
  float2* ftT = Xf + 196608;
  float2* ftB = ftT + 98304;

  k1a_rowdft<<<NIMG_IN * 2, 256, 0, stream>>>(x, y);
  k1b_coldft<<<NIMG_IN, 256, 0, stream>>>(y, Xf);
  k2_tw<<<NROWS / 16, 256, 0, stream>>>(t, w1r, w1i, w2r, w2i, tw1, tw2);
  k3_mix<<<(BB * OC * NV * 256) / 256, 256, 0, stream>>>(Xf, tw1, tw2, ftT, ftB);
  k4a_hdft<<<NIMG_OUT, 256, 0, stream>>>(ftT, ftB, G);
  k4b_wdft<<<NIMG_OUT * 8, 256, 0, stream>>>(G, out);
}

// Round 3
// 467.924 us; speedup vs baseline: 1.5267x; 1.0982x over previous
//
#include <hip/hip_runtime.h>

// Sizes
#define BB 16
#define IC 8
#define OC 8
#define NV 3
#define M1 16
#define M2 16
#define HH 256
#define WW 256
#define NIMG_IN  (BB*IC*NV)        // 384
#define NIMG_OUT (BB*OC*NV)        // 384
#define NROWS    (IC*OC*NV*M1*M2)  // 49152
#define TWO_PI 6.28318530717958647692f

// ---------------------------------------------------------------------------
// K1a: row DFT. grid = 768 (img, kx-half). block 256 = (col4 0..63, hq 0..3).
// Each thread: float4 x-loads over its 64-h slice, 9 kx accumulators in regs,
// twiddles via wave-uniform LDS broadcast. 2-round LDS reduction over hq.
// y[img][kx][w] = sum_h e^{-2pi i kx h/256} x[h][w], kx in 0..16.
// ---------------------------------------------------------------------------
__global__ __launch_bounds__(256, 4) void k1a_rowdft(const float* __restrict__ x,
                                                     float2* __restrict__ y) {
  __shared__ float2 tbl[256];
  __shared__ float red[2][64][73];  // 37.4 KB, stride 73 (odd) -> conflict-free
  const int tid = threadIdx.x;
  const int img = blockIdx.x >> 1;
  const int half = blockIdx.x & 1;
  const int kbase = half ? 9 : 0;
  const int kcount = half ? 8 : 9;
  {
    float s, c;
    sincosf((float)tid * (TWO_PI / 256.0f), &s, &c);
    tbl[tid] = make_float2(c, s);
  }
  __syncthreads();

  const int col4 = tid & 63;
  const int hq = tid >> 6;
  const float4* xp = (const float4*)(x + (size_t)img * 65536) + col4;

  float ar[9][4], ai[9][4];
#pragma unroll
  for (int j = 0; j < 9; j++)
#pragma unroll
    for (int c = 0; c < 4; c++) { ar[j][c] = 0.0f; ai[j][c] = 0.0f; }

  for (int hi = 0; hi < 64; hi++) {
    const int h = hq * 64 + hi;
    float4 xv = xp[(size_t)h * 64];
    int m = (kbase * h) & 255;
#pragma unroll
    for (int j = 0; j < 9; j++) {
      float2 e = tbl[m];  // wave-uniform -> broadcast
      m = (m + h) & 255;
      ar[j][0] = fmaf(e.x, xv.x, ar[j][0]);
      ai[j][0] = fmaf(-e.y, xv.x, ai[j][0]);
      ar[j][1] = fmaf(e.x, xv.y, ar[j][1]);
      ai[j][1] = fmaf(-e.y, xv.y, ai[j][1]);
      ar[j][2] = fmaf(e.x, xv.z, ar[j][2]);
      ai[j][2] = fmaf(-e.y, xv.z, ai[j][2]);
      ar[j][3] = fmaf(e.x, xv.w, ar[j][3]);
      ai[j][3] = fmaf(-e.y, xv.w, ai[j][3]);
    }
  }

  // reduce over hq (4 partials) in two rounds
  if (hq >= 2) {
    float* p = red[hq - 2][col4];
#pragma unroll
    for (int j = 0; j < 9; j++)
#pragma unroll
      for (int c = 0; c < 4; c++) { p[j * 8 + c * 2] = ar[j][c]; p[j * 8 + c * 2 + 1] = ai[j][c]; }
  }
  __syncthreads();
  if (hq < 2) {
    const float* p = red[hq][col4];
#pragma unroll
    for (int j = 0; j < 9; j++)
#pragma unroll
      for (int c = 0; c < 4; c++) { ar[j][c] += p[j * 8 + c * 2]; ai[j][c] += p[j * 8 + c * 2 + 1]; }
  }
  __syncthreads();
  if (hq == 1) {
    float* p = red[0][col4];
#pragma unroll
    for (int j = 0; j < 9; j++)
#pragma unroll
      for (int c = 0; c < 4; c++) { p[j * 8 + c * 2] = ar[j][c]; p[j * 8 + c * 2 + 1] = ai[j][c]; }
  }
  __syncthreads();
  if (hq == 0) {
    const float* p = red[0][col4];
    float2* yo = y + (size_t)img * 4352;
    for (int j = 0; j < kcount; j++) {
#pragma unroll
      for (int c = 0; c < 4; c++) {
        float rr = ar[j][c] + p[j * 8 + c * 2];
        float ii = ai[j][c] + p[j * 8 + c * 2 + 1];
        yo[(kbase + j) * 256 + col4 * 4 + c] = make_float2(rr, ii);
      }
    }
  }
}

// ---------------------------------------------------------------------------
// K1b: column DFT over retained ky modes. grid = 384 (img).
// ---------------------------------------------------------------------------
__global__ __launch_bounds__(256) void k1b_coldft(const float2* __restrict__ y,
                                                  float2* __restrict__ Xf) {
  __shared__ float2 tbl[256];
  __shared__ float2 yb[17 * 257];
  const int tid = threadIdx.x;
  const int img = blockIdx.x;
  {
    float s, c;
    sincosf((float)tid * (TWO_PI / 256.0f), &s, &c);
    tbl[tid] = make_float2(c, s);
  }
  const float2* yg = y + (size_t)img * 4352;
  for (int n = tid; n < 4352; n += 256) {
    int kx = n >> 8, w = n & 255;
    yb[kx * 257 + w] = yg[n];
  }
  __syncthreads();

  float2* XfImg = Xf + (size_t)img * 512;
  for (int n = tid; n < 512; n += 256) {
    int row = n >> 4, ky = n & 15;
    int kxl = (row < 16) ? row : (32 - row);
    float sgn = (row < 16) ? 1.0f : -1.0f;
    float Xr = 0.0f, Xi = 0.0f;
    int m = 0;
    for (int w2 = 0; w2 < 256; w2++) {
      float2 yv = yb[kxl * 257 + w2];
      float2 e = tbl[m];
      m = (m + ky) & 255;
      float yy = yv.y * sgn;
      Xr += yv.x * e.x + yy * e.y;
      Xi += yy * e.x - yv.x * e.y;
    }
    XfImg[n] = make_float2(Xr, Xi);
  }
}

// ---------------------------------------------------------------------------
// K2: tw[b][row] = sum_t t[b][t] * w[row][t].  grid = 3072 (16 rows/block).
// Coalesced float4 staging of w tiles into LDS (XOR swizzle, conflict-free),
// thread = (b, r) computes via broadcast t + swizzled w reads.
// Two passes: (w1r,w1i) then (w2r,w2i); LDS = 16.6 + 32 KB.
// ---------------------------------------------------------------------------
__global__ __launch_bounds__(256) void k2_tw(const float* __restrict__ t,
                                             const float* __restrict__ w1r,
                                             const float* __restrict__ w1i,
                                             const float* __restrict__ w2r,
                                             const float* __restrict__ w2i,
                                             float2* __restrict__ tw1,
                                             float2* __restrict__ tw2) {
  __shared__ float tL[16 * 260];          // [b][260], padded (65 float4 pitch)
  __shared__ float4 wA[2][16 * 64];       // [arr][row][t4 ^ (row&7)]
  const int tid = threadIdx.x;
  const int row0 = blockIdx.x * 16;
  const int b = tid >> 4;
  const int r = tid & 15;
  const int c = r & 7;

  // stage t (once): 1024 float4, coalesced
  {
    const float4* tg = (const float4*)t;
    float4* ts = (float4*)tL;
    for (int n = tid; n < 1024; n += 256) ts[(n >> 6) * 65 + (n & 63)] = tg[n];
  }

  float o1r, o1i, o2r, o2i;
  const float4* tb4 = (const float4*)tL + b * 65;

  for (int pass = 0; pass < 2; pass++) {
    const float* wa = pass ? w2r : w1r;
    const float* wb = pass ? w2i : w1i;
    // stage w pair, coalesced with XOR swizzle
    const float4* ga = (const float4*)(wa + (size_t)row0 * 256);
    const float4* gb = (const float4*)(wb + (size_t)row0 * 256);
    for (int n = tid; n < 1024; n += 256) {
      int rr = n >> 6, t4 = n & 63;
      int sidx = (rr << 6) | (t4 ^ (rr & 7));
      wA[0][sidx] = ga[n];
      wA[1][sidx] = gb[n];
    }
    __syncthreads();

    const float4* ra4 = wA[0] + (r << 6);
    const float4* rb4 = wA[1] + (r << 6);
    float arr = 0.0f, aii = 0.0f;
#pragma unroll 8
    for (int t4 = 0; t4 < 64; t4++) {
      float4 tv = tb4[t4];        // broadcast within 16-lane b-group
      int s = t4 ^ c;
      float4 va = ra4[s];
      float4 vb = rb4[s];
      arr += tv.x * va.x + tv.y * va.y + tv.z * va.z + tv.w * va.w;
      aii += tv.x * vb.x + tv.y * vb.y + tv.z * vb.z + tv.w * vb.w;
    }
    if (pass) { o2r = arr; o2i = aii; } else { o1r = arr; o1i = aii; }
    __syncthreads();  // protect wA before restage / exit
  }

  tw1[(size_t)b * NROWS + row0 + r] = make_float2(o1r, o1i);
  tw2[(size_t)b * NROWS + row0 + r] = make_float2(o2r, o2i);
}

// ---------------------------------------------------------------------------
// K3: spectral mixing over input channels.
// ---------------------------------------------------------------------------
__global__ __launch_bounds__(256) void k3_mix(const float2* __restrict__ Xf,
                                              const float2* __restrict__ tw1,
                                              const float2* __restrict__ tw2,
                                              float2* __restrict__ ftT,
                                              float2* __restrict__ ftB) {
  const int n = blockIdx.x * 256 + threadIdx.x;
  const int xy = n & 255;
  const int ov = n >> 8;
  const int v = ov % 3;
  const int o = (ov / 3) & 7;
  const int b = n / (OC * NV * 256);

  float tr = 0.0f, ti2 = 0.0f, br = 0.0f, bi = 0.0f;
#pragma unroll
  for (int i = 0; i < IC; i++) {
    const float2 xt = Xf[(size_t)(((b * IC + i) * NV + v) << 9) + xy];
    const float2 xb = Xf[(size_t)(((b * IC + i) * NV + v) << 9) + 256 + xy];
    const int r = ((i * OC + o) * NV + v) * 256 + xy;
    float2 u1 = tw1[(size_t)b * NROWS + r];
    float2 u2 = tw2[(size_t)b * NROWS + r];
    tr += xt.x * u1.x - xt.y * u1.y;
    ti2 += xt.x * u1.y + xt.y * u1.x;
    br += xb.x * u2.x - xb.y * u2.y;
    bi += xb.x * u2.y + xb.y * u2.x;
  }
  const int nout = ((b * OC + o) * NV + v) * 256 + xy;
  ftT[nout] = make_float2(tr, ti2);
  ftB[nout] = make_float2(br, bi);
}

// ---------------------------------------------------------------------------
// K4a: G[img][ky][h] = sum_row ft[row][ky] e^{+2pi i kx_row h/256}. grid=384.
// ---------------------------------------------------------------------------
__global__ __launch_bounds__(256) void k4a_hdft(const float2* __restrict__ ftT,
                                                const float2* __restrict__ ftB,
                                                float2* __restrict__ G) {
  __shared__ float2 tbl[256];
  __shared__ float2 ftL[512];
  const int tid = threadIdx.x;
  const int img = blockIdx.x;
  {
    float s, c;
    sincosf((float)tid * (TWO_PI / 256.0f), &s, &c);
    tbl[tid] = make_float2(c, s);
    ftL[tid] = ftT[(size_t)img * 256 + tid];
    ftL[256 + tid] = ftB[(size_t)img * 256 + tid];
  }
  __syncthreads();

  const int h = tid;
  float gr[16], gi[16];
#pragma unroll
  for (int ky = 0; ky < 16; ky++) { gr[ky] = 0.0f; gi[ky] = 0.0f; }
  for (int row = 0; row < 32; row++) {
    int kxv = (row < 16) ? row : (224 + row);
    float2 e = tbl[(kxv * h) & 255];
#pragma unroll
    for (int ky = 0; ky < 16; ky++) {
      float2 f = ftL[row * 16 + ky];
      gr[ky] += f.x * e.x - f.y * e.y;
      gi[ky] += f.x * e.y + f.y * e.x;
    }
  }
  float2* Gi = G + (size_t)img * 4096;
#pragma unroll
  for (int ky = 0; ky < 16; ky++) Gi[ky * 256 + h] = make_float2(gr[ky], gi[ky]);
}

// ---------------------------------------------------------------------------
// K4b: out[h][w] = sum_ky Re(P[ky][w] * G[ky][h]). grid = 384*8.
// ---------------------------------------------------------------------------
__global__ __launch_bounds__(256) void k4b_wdft(const float2* __restrict__ G,
                                                float* __restrict__ out) {
  __shared__ float2 tbl[256];
  __shared__ float2 PL[16 * 256];
  __shared__ float2 gt[512];
  const int tid = threadIdx.x;
  const int img = blockIdx.x >> 3;
  const int h0 = (blockIdx.x & 7) * 32;
  {
    float s, c;
    sincosf((float)tid * (TWO_PI / 256.0f), &s, &c);
    tbl[tid] = make_float2(c, s);
  }
  __syncthreads();
  for (int n = tid; n < 4096; n += 256) {
    int ky = n >> 8, w = n & 255;
    float2 e = tbl[(ky * w) & 255];
    float sc = (ky == 0) ? (1.0f / 65536.0f) : (2.0f / 65536.0f);
    PL[n] = make_float2(e.x * sc, e.y * sc);
  }
  const float2* Gi = G + (size_t)img * 4096;
  for (int n = tid; n < 512; n += 256) {
    int ky = n >> 5, hh = n & 31;
    gt[n] = Gi[ky * 256 + h0 + hh];
  }
  __syncthreads();

  const int w0 = tid & 63;
  const int hq = tid >> 6;
  float acc[8][4];
#pragma unroll
  for (int a = 0; a < 8; a++)
#pragma unroll
    for (int j = 0; j < 4; j++) acc[a][j] = 0.0f;

#pragma unroll 4
  for (int ky = 0; ky < 16; ky++) {
    float2 p0 = PL[ky * 256 + w0];
    float2 p1 = PL[ky * 256 + w0 + 64];
    float2 p2 = PL[ky * 256 + w0 + 128];
    float2 p3 = PL[ky * 256 + w0 + 192];
#pragma unroll
    for (int a = 0; a < 8; a++) {
      float2 g = gt[ky * 32 + hq * 8 + a];
      acc[a][0] += g.x * p0.x - g.y * p0.y;
      acc[a][1] += g.x * p1.x - g.y * p1.y;
      acc[a][2] += g.x * p2.x - g.y * p2.y;
      acc[a][3] += g.x * p3.x - g.y * p3.y;
    }
  }
  float* obase = out + (size_t)img * 65536 + (size_t)(h0 + hq * 8) * 256;
#pragma unroll
  for (int a = 0; a < 8; a++) {
#pragma unroll
    for (int j = 0; j < 4; j++) obase[a * 256 + w0 + 64 * j] = acc[a][j];
  }
}

// ---------------------------------------------------------------------------
extern "C" void kernel_launch(void* const* d_in, const int* in_sizes, int n_in,
                              void* d_out, int out_size, void* d_ws, size_t ws_size,
                              hipStream_t stream) {
  const float* t = (const float*)d_in[0];
  const float* x = (const float*)d_in[1];
  const float* w1r = (const float*)d_in[2];
  const float* w1i = (const float*)d_in[3];
  const float* w2r = (const float*)d_in[4];
  const float* w2i = (const float*)d_in[5];
  float* out = (float*)d_out;

  float2* R1 = (float2*)d_ws;
  float2* y = R1;
  float2* tw1 = R1;
  float2* tw2 = R1 + 786432;
  float2* G = R1;
  float2* Xf = R1 + 1671168;
  float2* ftT = Xf + 196608;
  float2* ftB = ftT + 98304;

  k1a_rowdft<<<NIMG_IN * 2, 256, 0, stream>>>(x, y);
  k1b_coldft<<<NIMG_IN, 256, 0, stream>>>(y, Xf);
  k2_tw<<<NROWS / 16, 256, 0, stream>>>(t, w1r, w1i, w2r, w2i, tw1, tw2);
  k3_mix<<<(BB * OC * NV * 256) / 256, 256, 0, stream>>>(Xf, tw1, tw2, ftT, ftB);
  k4a_hdft<<<NIMG_OUT, 256, 0, stream>>>(ftT, ftB, G);
  k4b_wdft<<<NIMG_OUT * 8, 256, 0, stream>>>(G, out);
}